// Round 1
// baseline (1289.973 us; speedup 1.0000x reference)
//
#include <hip/hip_runtime.h>
#include <math.h>

// Problem constants (fixed by the reference)
#define HD 512          // Q_DIM = F_DIM = H_DIM = OUT_DIM = 512
#define SP 129          // S+1 = T+1
#define NBATCH 16
#define LQ 256
#define MQ (NBATCH*LQ)  // 4096 query rows
#define SCALE 0.04419417382415922f  // 1/sqrt(512)

// ---------------------------------------------------------------------------
// fp32 GEMM: C[M,N] = A[M,K] @ W[K,N] + bias, with output row remap
// (rpb_in -> rpb_out rows per batch, to leave a gap for the pad row).
// 64x64 tile, 256 threads, 4x4 micro, k-major LDS staging, float4 LDS reads.
// ---------------------------------------------------------------------------
__global__ __launch_bounds__(256) void gemm_bias(
    const float* __restrict__ A, const float* __restrict__ W,
    const float* __restrict__ bias, float* __restrict__ C,
    int M, int N, int K, int rpb_in, int rpb_out)
{
  __shared__ float At[16*68];  // [k][m], pad 68 (272B, 16B-aligned rows)
  __shared__ float Bt[16*68];  // [k][n]
  const int tid = threadIdx.x;
  const int tx = tid & 15, ty = tid >> 4;
  const int bm = blockIdx.x * 64, bn = blockIdx.y * 64;
  const int c  = tid & 15, r0 = tid >> 4;
  const int cb = tid & 63, rb0 = tid >> 6;
  float acc[4][4] = {};

  for (int k0 = 0; k0 < K; k0 += 16) {
    #pragma unroll
    for (int i = 0; i < 4; ++i) {
      int r = r0 + 16*i;
      At[c*68 + r] = A[(size_t)(bm + r)*K + (k0 + c)];
    }
    #pragma unroll
    for (int i = 0; i < 4; ++i) {
      int r = rb0 + 4*i;
      Bt[r*68 + cb] = W[(size_t)(k0 + r)*N + (bn + cb)];
    }
    __syncthreads();
    #pragma unroll
    for (int kk = 0; kk < 16; ++kk) {
      const float4 a4 = *(const float4*)&At[kk*68 + ty*4];
      const float4 b4 = *(const float4*)&Bt[kk*68 + tx*4];
      const float av[4] = {a4.x, a4.y, a4.z, a4.w};
      const float bv[4] = {b4.x, b4.y, b4.z, b4.w};
      #pragma unroll
      for (int i = 0; i < 4; ++i)
        #pragma unroll
        for (int j = 0; j < 4; ++j)
          acc[i][j] = fmaf(av[i], bv[j], acc[i][j]);
    }
    __syncthreads();
  }
  #pragma unroll
  for (int i = 0; i < 4; ++i) {
    int m = bm + ty*4 + i;
    int mo = (m / rpb_in) * rpb_out + (m % rpb_in);
    #pragma unroll
    for (int j = 0; j < 4; ++j) {
      int n = bn + tx*4 + j;
      C[(size_t)mo*N + n] = acc[i][j] + bias[n];
    }
  }
}

// Fill pad row 128 of each batch with the bias vector (zero row @ W + b = b).
__global__ void write_pad(float* __restrict__ skey, const float* __restrict__ bs,
                          float* __restrict__ tkey, const float* __restrict__ bt)
{
  int i = blockIdx.x * 256 + threadIdx.x;   // 16*512 total
  int b = i >> 9, k = i & 511;
  skey[((size_t)b*SP + 128)*HD + k] = bs[k];
  tkey[((size_t)b*SP + 128)*HD + k] = bt[k];
}

// ---------------------------------------------------------------------------
// Fused trilinear attention. One block = 2 query rows (share key tiles).
// scores S[s,t] = sum_k q[k]*s_key[s,k]*t_key[t,k] * SCALE, softmax over
// flattened 129x129, then s_ctx = (rowsum P) @ s_key, t_ctx = (colsum P) @ t_key.
// ---------------------------------------------------------------------------
__global__ __launch_bounds__(256, 2) void attn_kernel(
    const float* __restrict__ qg,     // (4096, 512)
    const float* __restrict__ s_key,  // (16, 129, 512)
    const float* __restrict__ t_key,  // (16, 129, 512)
    float* __restrict__ s_ctx,        // (4096, 512)
    float* __restrict__ t_ctx)        // (4096, 512)
{
  __shared__ float Sbuf[SP*SP];        // 16641 f32 = 66.5 KB (also staging alias)
  __shared__ float qs0[HD], qs1[HD];
  __shared__ float wrow[SP], wcol[SP];
  __shared__ float red[4];

  const int tid  = threadIdx.x;
  // XCD-chunked swizzle: 2048 blocks, 8 XCDs -> 256 consecutive work items per XCD
  const int bid  = ((int)blockIdx.x & 7) * 256 + ((int)blockIdx.x >> 3);
  const int gid0 = bid * 2;            // first of the two (b*L + l) rows
  const int b    = gid0 >> 8;          // / 256 (rows per batch)
  const float* qr0 = qg + (size_t)gid0 * HD;
  const float* qr1 = qr0 + HD;
  const float* sk  = s_key + (size_t)b * SP * HD;
  const float* tk  = t_key + (size_t)b * SP * HD;

  for (int k = tid; k < HD; k += 256) { qs0[k] = qr0[k]; qs1[k] = qr1[k]; }

  // k-major staging tiles alias the score buffer (regs hold acc meanwhile)
  float* skt = Sbuf;                   // [16][132], XOR-swizzled row index
  float* tkt = Sbuf + 16*132;

  const int tx = tid & 15, ty = tid >> 4;
  const int wave = tid >> 6, lane = tid & 63;
  const int c = tid & 15, r0 = tid >> 4;

  float acc0[8][8] = {}, acc1[8][8] = {};

  const int a_base0 = (ty*8)     ^ (ty & 12);
  const int a_base1 = (ty*8 + 4) ^ (ty & 12);
  const int b_base0 = (tx*8)     ^ (tx & 12);
  const int b_base1 = (tx*8 + 4) ^ (tx & 12);

  for (int k0 = 0; k0 < HD; k0 += 16) {
    #pragma unroll
    for (int i = 0; i < 8; ++i) {
      int r  = r0 + 16*i;
      int rs = r ^ ((r >> 3) & 0xC);   // bank swizzle (flips bits 2,3 by bits 5,6)
      skt[c*132 + rs] = sk[(size_t)r*HD + k0 + c];
      tkt[c*132 + rs] = tk[(size_t)r*HD + k0 + c];
    }
    __syncthreads();
    #pragma unroll 2
    for (int kk = 0; kk < 16; ++kk) {
      const float4 A0 = *(const float4*)&skt[kk*132 + a_base0];
      const float4 A1 = *(const float4*)&skt[kk*132 + a_base1];
      const float4 B0 = *(const float4*)&tkt[kk*132 + b_base0];
      const float4 B1 = *(const float4*)&tkt[kk*132 + b_base1];
      const float q0v = qs0[k0+kk], q1v = qs1[k0+kk];
      const float av[8] = {A0.x,A0.y,A0.z,A0.w,A1.x,A1.y,A1.z,A1.w};
      const float bv[8] = {B0.x,B0.y,B0.z,B0.w,B1.x,B1.y,B1.z,B1.w};
      #pragma unroll
      for (int i = 0; i < 8; ++i) {
        float p0 = q0v * av[i];
        float p1 = q1v * av[i];
        #pragma unroll
        for (int j = 0; j < 8; ++j) {
          acc0[i][j] = fmaf(p0, bv[j], acc0[i][j]);
          acc1[i][j] = fmaf(p1, bv[j], acc1[i][j]);
        }
      }
    }
    __syncthreads();
  }

  // Per-query softmax + context, sequentially reusing Sbuf.
  auto process = [&](float (&acc)[8][8], const float* qsl, int gid) {
    // scores -> LDS (main 128x128 block)
    #pragma unroll
    for (int i = 0; i < 8; ++i)
      #pragma unroll
      for (int j = 0; j < 8; ++j)
        Sbuf[(ty*8 + i)*SP + (tx*8 + j)] = acc[i][j] * SCALE;

    // border: row/col 128 (pad key rows), 257 wave-reduced dots
    for (int e = wave; e < 257; e += 4) {
      int si = (e < 128) ? e   : 128;
      int ti = (e < 128) ? 128 : (e - 128);
      const float* srow = sk + (size_t)si*HD;
      const float* trow = tk + (size_t)ti*HD;
      float sum = 0.f;
      for (int k = lane; k < HD; k += 64) sum += qsl[k] * srow[k] * trow[k];
      #pragma unroll
      for (int off = 32; off > 0; off >>= 1) sum += __shfl_down(sum, off);
      if (lane == 0) Sbuf[si*SP + ti] = sum * SCALE;
    }
    __syncthreads();

    // global max
    float lmax = -1e30f;
    for (int idx = tid; idx < SP*SP; idx += 256) lmax = fmaxf(lmax, Sbuf[idx]);
    #pragma unroll
    for (int off = 32; off > 0; off >>= 1) lmax = fmaxf(lmax, __shfl_down(lmax, off));
    if (lane == 0) red[wave] = lmax;
    __syncthreads();
    const float gmax = fmaxf(fmaxf(red[0], red[1]), fmaxf(red[2], red[3]));

    // exp in place
    for (int idx = tid; idx < SP*SP; idx += 256) Sbuf[idx] = __expf(Sbuf[idx] - gmax);
    __syncthreads();

    // row sums (threads 0..128) and col sums (threads 127..255)
    if (tid < SP) {
      float s = 0.f;
      for (int j = 0; j < SP; ++j) s += Sbuf[tid*SP + j];
      wrow[tid] = s;
    }
    if (tid >= 127) {
      int c2 = tid - 127;
      if (c2 < SP) {
        float s = 0.f;
        for (int i2 = 0; i2 < SP; ++i2) s += Sbuf[i2*SP + c2];
        wcol[c2] = s;
      }
    }
    __syncthreads();

    // Z and 1/Z
    if (tid < 64) {
      float z = wrow[tid] + wrow[tid + 64];
      if (tid == 0) z += wrow[128];
      #pragma unroll
      for (int off = 32; off > 0; off >>= 1) z += __shfl_down(z, off);
      if (tid == 0) red[0] = 1.0f / z;
    }
    __syncthreads();
    const float invZ = red[0];

    // contexts: s_ctx[k] = invZ * sum_s wrow[s]*s_key[s,k]; t_ctx analog
    float* so = s_ctx + (size_t)gid*HD;
    float* to = t_ctx + (size_t)gid*HD;
    for (int k = tid; k < HD; k += 256) {
      float sa = 0.f, ta = 0.f;
      for (int s2 = 0; s2 < SP; ++s2) {
        sa = fmaf(wrow[s2], sk[(size_t)s2*HD + k], sa);
        ta = fmaf(wcol[s2], tk[(size_t)s2*HD + k], ta);
      }
      so[k] = sa * invZ;
      to[k] = ta * invZ;
    }
    __syncthreads();   // protect Sbuf/wrow/wcol for the next query
  };

  process(acc0, qs0, gid0);
  process(acc1, qs1, gid0 + 1);
}

// ---------------------------------------------------------------------------
// out = tanh([query | s_ctx | t_ctx] @ Wo + bo) ; K = 3*512, segments never
// cross a 16-wide k-tile.
// ---------------------------------------------------------------------------
__global__ __launch_bounds__(256) void gemm3_tanh(
    const float* __restrict__ A0, const float* __restrict__ A1,
    const float* __restrict__ A2, const float* __restrict__ W,
    const float* __restrict__ bias, float* __restrict__ C, int M, int N)
{
  __shared__ float At[16*68];
  __shared__ float Bt[16*68];
  const int tid = threadIdx.x;
  const int tx = tid & 15, ty = tid >> 4;
  const int bm = blockIdx.x * 64, bn = blockIdx.y * 64;
  const int c  = tid & 15, r0 = tid >> 4;
  const int cb = tid & 63, rb0 = tid >> 6;
  float acc[4][4] = {};

  for (int k0 = 0; k0 < 1536; k0 += 16) {
    const float* Ap = (k0 < 512) ? A0 : (k0 < 1024) ? A1 : A2;
    const int kloc = k0 & 511;
    #pragma unroll
    for (int i = 0; i < 4; ++i) {
      int r = r0 + 16*i;
      At[c*68 + r] = Ap[(size_t)(bm + r)*512 + (kloc + c)];
    }
    #pragma unroll
    for (int i = 0; i < 4; ++i) {
      int r = rb0 + 4*i;
      Bt[r*68 + cb] = W[(size_t)(k0 + r)*N + (bn + cb)];
    }
    __syncthreads();
    #pragma unroll
    for (int kk = 0; kk < 16; ++kk) {
      const float4 a4 = *(const float4*)&At[kk*68 + ty*4];
      const float4 b4 = *(const float4*)&Bt[kk*68 + tx*4];
      const float av[4] = {a4.x, a4.y, a4.z, a4.w};
      const float bv[4] = {b4.x, b4.y, b4.z, b4.w};
      #pragma unroll
      for (int i = 0; i < 4; ++i)
        #pragma unroll
        for (int j = 0; j < 4; ++j)
          acc[i][j] = fmaf(av[i], bv[j], acc[i][j]);
    }
    __syncthreads();
  }
  #pragma unroll
  for (int i = 0; i < 4; ++i) {
    int m = bm + ty*4 + i;
    #pragma unroll
    for (int j = 0; j < 4; ++j) {
      int n = bn + tx*4 + j;
      C[(size_t)m*N + n] = tanhf(acc[i][j] + bias[n]);
    }
  }
}

extern "C" void kernel_launch(void* const* d_in, const int* in_sizes, int n_in,
                              void* d_out, int out_size, void* d_ws, size_t ws_size,
                              hipStream_t stream) {
  (void)in_sizes; (void)n_in; (void)out_size; (void)ws_size;
  const float* query = (const float*)d_in[0];
  const float* src   = (const float*)d_in[1];
  const float* trg   = (const float*)d_in[2];
  const float* Wq    = (const float*)d_in[3];
  const float* bq    = (const float*)d_in[4];
  const float* Wsm   = (const float*)d_in[5];
  const float* bs    = (const float*)d_in[6];
  const float* Wtm   = (const float*)d_in[7];
  const float* bt    = (const float*)d_in[8];
  const float* Wo    = (const float*)d_in[9];
  const float* bo    = (const float*)d_in[10];
  float* out = (float*)d_out;

  // workspace layout (floats): q | s_key | t_key | s_ctx | t_ctx  (~34 MB)
  float* wsf  = (float*)d_ws;
  float* qbuf = wsf;
  float* skey = qbuf + (size_t)MQ*HD;
  float* tkey = skey + (size_t)NBATCH*SP*HD;
  float* sctx = tkey + (size_t)NBATCH*SP*HD;
  float* tctx = sctx + (size_t)MQ*HD;

  dim3 blk(256);
  // q = query @ Wq + bq         (4096 x 512)
  gemm_bias<<<dim3(MQ/64, HD/64), blk, 0, stream>>>(query, Wq, bq, qbuf,
                                                    MQ, HD, HD, 256, 256);
  // s_key/t_key main rows (128 per batch), remapped into 129-row layout
  gemm_bias<<<dim3(2048/64, HD/64), blk, 0, stream>>>(src, Wsm, bs, skey,
                                                      2048, HD, HD, 128, SP);
  gemm_bias<<<dim3(2048/64, HD/64), blk, 0, stream>>>(trg, Wtm, bt, tkey,
                                                      2048, HD, HD, 128, SP);
  // pad rows = bias
  write_pad<<<dim3(32), blk, 0, stream>>>(skey, bs, tkey, bt);
  // fused trilinear attention (2 query rows per block)
  attn_kernel<<<dim3(MQ/2), blk, 0, stream>>>(qbuf, skey, tkey, sctx, tctx);
  // out = tanh([query|s_ctx|t_ctx] @ Wo + bo)
  gemm3_tanh<<<dim3(MQ/64, HD/64), blk, 0, stream>>>(query, sctx, tctx, Wo, bo,
                                                     out, MQ, HD);
}

// Round 2
// 718.585 us; speedup vs baseline: 1.7952x; 1.7952x over previous
//
#include <hip/hip_runtime.h>
#include <math.h>

// Problem constants (fixed by the reference)
#define HD 512          // Q_DIM = F_DIM = H_DIM = OUT_DIM = 512
#define SP 129          // S+1 = T+1
#define RPAD 160        // padded key rows per batch (129 used, rest zero)
#define NBATCH 16
#define LQ 256
#define MQ (NBATCH*LQ)  // 4096 query rows
#define SCALE 0.04419417382415922f  // 1/sqrt(512)

typedef short bf16x8 __attribute__((ext_vector_type(8)));
typedef float f32x4  __attribute__((ext_vector_type(4)));

__device__ __forceinline__ unsigned short f2bf(float f) {
  unsigned u = __float_as_uint(f);
  unsigned r = (u + 0x7FFFu + ((u >> 16) & 1u)) >> 16;   // RNE
  return (unsigned short)r;
}
__device__ __forceinline__ float bf2f(unsigned short h) {
  return __uint_as_float(((unsigned)h) << 16);
}

// ---------------------------------------------------------------------------
// fp32 GEMM: C[M,N] = A[M,K] @ W[K,N] + bias (used for q = query @ Wq + bq)
// ---------------------------------------------------------------------------
__global__ __launch_bounds__(256) void gemm_bias(
    const float* __restrict__ A, const float* __restrict__ W,
    const float* __restrict__ bias, float* __restrict__ C,
    int M, int N, int K)
{
  __shared__ float At[16*68];
  __shared__ float Bt[16*68];
  const int tid = threadIdx.x;
  const int tx = tid & 15, ty = tid >> 4;
  const int bm = blockIdx.x * 64, bn = blockIdx.y * 64;
  const int c  = tid & 15, r0 = tid >> 4;
  const int cb = tid & 63, rb0 = tid >> 6;
  float acc[4][4] = {};

  for (int k0 = 0; k0 < K; k0 += 16) {
    #pragma unroll
    for (int i = 0; i < 4; ++i) {
      int r = r0 + 16*i;
      At[c*68 + r] = A[(size_t)(bm + r)*K + (k0 + c)];
    }
    #pragma unroll
    for (int i = 0; i < 4; ++i) {
      int r = rb0 + 4*i;
      Bt[r*68 + cb] = W[(size_t)(k0 + r)*N + (bn + cb)];
    }
    __syncthreads();
    #pragma unroll
    for (int kk = 0; kk < 16; ++kk) {
      const float4 a4 = *(const float4*)&At[kk*68 + ty*4];
      const float4 b4 = *(const float4*)&Bt[kk*68 + tx*4];
      const float av[4] = {a4.x, a4.y, a4.z, a4.w};
      const float bv[4] = {b4.x, b4.y, b4.z, b4.w};
      #pragma unroll
      for (int i = 0; i < 4; ++i)
        #pragma unroll
        for (int j = 0; j < 4; ++j)
          acc[i][j] = fmaf(av[i], bv[j], acc[i][j]);
    }
    __syncthreads();
  }
  #pragma unroll
  for (int i = 0; i < 4; ++i) {
    int m = bm + ty*4 + i;
    #pragma unroll
    for (int j = 0; j < 4; ++j) {
      int n = bn + tx*4 + j;
      C[(size_t)m*N + n] = acc[i][j] + bias[n];
    }
  }
}

// ---------------------------------------------------------------------------
// Same GEMM but bf16 output with row remap 128-per-batch -> 160-per-batch
// (key GEMMs; rows 128..159 of each batch filled by write_pad_bf16)
// ---------------------------------------------------------------------------
__global__ __launch_bounds__(256) void gemm_bias_bf16(
    const float* __restrict__ A, const float* __restrict__ W,
    const float* __restrict__ bias, unsigned short* __restrict__ C,
    int M, int N, int K)
{
  __shared__ float At[16*68];
  __shared__ float Bt[16*68];
  const int tid = threadIdx.x;
  const int tx = tid & 15, ty = tid >> 4;
  const int bm = blockIdx.x * 64, bn = blockIdx.y * 64;
  const int c  = tid & 15, r0 = tid >> 4;
  const int cb = tid & 63, rb0 = tid >> 6;
  float acc[4][4] = {};

  for (int k0 = 0; k0 < K; k0 += 16) {
    #pragma unroll
    for (int i = 0; i < 4; ++i) {
      int r = r0 + 16*i;
      At[c*68 + r] = A[(size_t)(bm + r)*K + (k0 + c)];
    }
    #pragma unroll
    for (int i = 0; i < 4; ++i) {
      int r = rb0 + 4*i;
      Bt[r*68 + cb] = W[(size_t)(k0 + r)*N + (bn + cb)];
    }
    __syncthreads();
    #pragma unroll
    for (int kk = 0; kk < 16; ++kk) {
      const float4 a4 = *(const float4*)&At[kk*68 + ty*4];
      const float4 b4 = *(const float4*)&Bt[kk*68 + tx*4];
      const float av[4] = {a4.x, a4.y, a4.z, a4.w};
      const float bv[4] = {b4.x, b4.y, b4.z, b4.w};
      #pragma unroll
      for (int i = 0; i < 4; ++i)
        #pragma unroll
        for (int j = 0; j < 4; ++j)
          acc[i][j] = fmaf(av[i], bv[j], acc[i][j]);
    }
    __syncthreads();
  }
  #pragma unroll
  for (int i = 0; i < 4; ++i) {
    int m = bm + ty*4 + i;           // 0..2047, 128 rows per batch
    int mo = (m >> 7) * RPAD + (m & 127);
    #pragma unroll
    for (int j = 0; j < 4; ++j) {
      int n = bn + tx*4 + j;
      C[(size_t)mo*N + n] = f2bf(acc[i][j] + bias[n]);
    }
  }
}

// Rows 128..159 of each batch: row 128 = bias (the reference pad row after
// the key linear), rows 129..159 = 0 (MFMA padding; masked in softmax).
__global__ void write_pad_bf16(unsigned short* __restrict__ skey, const float* __restrict__ bs,
                               unsigned short* __restrict__ tkey, const float* __restrict__ bt)
{
  int i = blockIdx.x * 256 + threadIdx.x;   // 16 batches * 32 rows * 512
  int b = i >> 14;                          // /(32*512)
  int r = 128 + ((i >> 9) & 31);
  int k = i & 511;
  size_t off = ((size_t)b*RPAD + r)*HD + k;
  unsigned short vs = (r == 128) ? f2bf(bs[k]) : 0;
  unsigned short vt = (r == 128) ? f2bf(bt[k]) : 0;
  skey[off] = vs;
  tkey[off] = vt;
}

// ---------------------------------------------------------------------------
// Fused trilinear attention with bf16 MFMA. One block (4 waves) per query row.
// Scores S[s,t] = sum_k (q[k]*sk[s,k]) * tk[t,k], M=N padded to 144 (9 tiles);
// row 128 of the key buffers is the reference's pad row, so the softmax border
// falls out of the MFMA. P is never materialized: softmax needs only
// gmax, row sums ws and col sums wt; then s_ctx = ws@s_key, t_ctx = wt@t_key.
// ---------------------------------------------------------------------------
__global__ __launch_bounds__(256) void attn_kernel(
    const float* __restrict__ qg,            // (4096, 512) f32
    const unsigned short* __restrict__ s_key, // (16, 160, 512) bf16
    const unsigned short* __restrict__ t_key, // (16, 160, 512) bf16
    float* __restrict__ s_ctx,               // (4096, 512) f32
    float* __restrict__ t_ctx)               // (4096, 512) f32
{
  __shared__ __align__(16) unsigned short skt[144*64];  // XOR-swizzled K-tile
  __shared__ __align__(16) unsigned short tkt[144*64];
  __shared__ __align__(16) float qs[HD];
  __shared__ float ws_p[2][144];   // row-sum partials, indexed by col-block
  __shared__ float wt_p[2][144];   // col-sum partials, indexed by row-block
  __shared__ float red[8];

  const int tid  = threadIdx.x;
  const int lane = tid & 63;
  const int w    = tid >> 6;
  const int rb   = w & 1;    // tile-row block: rows {0..4} or {4..8} (overlap tr=4)
  const int cbk  = w >> 1;   // tile-col block: cols {0..4} or {4..8} (overlap tc=4)
  const int fq   = lane >> 4;    // 0..3
  const int fr   = lane & 15;    // 0..15

  // XCD-chunked swizzle: 4096 blocks -> 512 consecutive rows per XCD
  const int gid = ((int)blockIdx.x & 7) * 512 + ((int)blockIdx.x >> 3);
  const int b   = gid >> 8;
  const float* qr = qg + (size_t)gid * HD;
  const unsigned short* skg = s_key + (size_t)b * RPAD * HD;
  const unsigned short* tkg = t_key + (size_t)b * RPAD * HD;

  for (int k = tid; k < HD; k += 256) qs[k] = qr[k];

  f32x4 acc[5][5] = {};

  for (int kt = 0; kt < 8; ++kt) {
    const int k0 = kt * 64;
    // ---- stage 144 rows x 64 cols of both keys, XOR-swizzled ----
    #pragma unroll
    for (int i = 0; i < 5; ++i) {
      int idx = tid + 256*i;
      if (idx < 1152) {
        int r = idx >> 3, c = idx & 7;      // row, 16B chunk (8 bf16)
        size_t goff = ((size_t)r << 9) + k0 + (c << 3);
        const uint4 vs = *(const uint4*)(skg + goff);
        const uint4 vt = *(const uint4*)(tkg + goff);
        int o = ((r << 7) + (c << 4)) ^ ((r & 7) << 4);   // byte offset
        *(uint4*)((char*)skt + o) = vs;
        *(uint4*)((char*)tkt + o) = vt;
      }
    }
    __syncthreads();
    // ---- MFMA: 2 substeps of K=32 ----
    #pragma unroll
    for (int ks = 0; ks < 2; ++ks) {
      float qv[8];
      const int kq = k0 + ks*32 + fq*8;
      #pragma unroll
      for (int e = 0; e < 8; ++e) qv[e] = qs[kq + e];
      bf16x8 af[5], bf_[5];
      #pragma unroll
      for (int i = 0; i < 5; ++i) {
        // A = q-scaled s_key fragment; rows 16*(rb*4+i)+fr
        int ra = 16*(rb*4 + i) + fr;
        int oa = ((ra << 7) + ks*64 + (fq << 4)) ^ ((ra & 7) << 4);
        bf16x8 raw = *(const bf16x8*)((const char*)skt + oa);
        bf16x8 sc;
        #pragma unroll
        for (int e = 0; e < 8; ++e)
          sc[e] = (short)f2bf(bf2f((unsigned short)raw[e]) * qv[e]);
        af[i] = sc;
        // B = t_key fragment; rows 16*(cbk*4+i)+fr
        int rbx = 16*(cbk*4 + i) + fr;
        int ob = ((rbx << 7) + ks*64 + (fq << 4)) ^ ((rbx & 7) << 4);
        bf_[i] = *(const bf16x8*)((const char*)tkt + ob);
      }
      #pragma unroll
      for (int i = 0; i < 5; ++i)
        #pragma unroll
        for (int j = 0; j < 5; ++j)
          acc[i][j] = __builtin_amdgcn_mfma_f32_16x16x32_bf16(af[i], bf_[j], acc[i][j], 0, 0, 0);
    }
    __syncthreads();
  }

  // ---- masked max over valid (s<129, t<129) ----
  // tile-row tr=rb*4+i: only tr==8 partial (valid iff fq==0 && r==0);
  // tile-col tc=cbk*4+j: only tc==8 partial (valid iff fr==0).
  float m = -3e38f;
  #pragma unroll
  for (int i = 0; i < 5; ++i) {
    const bool row_full = (rb*4 + i) < 8;
    #pragma unroll
    for (int j = 0; j < 5; ++j) {
      const bool col_full = (cbk*4 + j) < 8;
      #pragma unroll
      for (int r = 0; r < 4; ++r) {
        bool ok = (row_full || (fq == 0 && r == 0)) && (col_full || (fr == 0));
        float v = acc[i][j][r];
        m = ok ? fmaxf(m, v) : m;
      }
    }
  }
  #pragma unroll
  for (int off = 32; off > 0; off >>= 1) m = fmaxf(m, __shfl_xor(m, off));
  if (lane == 0) red[w] = m;
  __syncthreads();
  const float gmax = fmaxf(fmaxf(red[0], red[1]), fmaxf(red[2], red[3])) * SCALE;

  // ---- exp in registers (invalid -> 0) ----
  #pragma unroll
  for (int i = 0; i < 5; ++i) {
    const bool row_full = (rb*4 + i) < 8;
    #pragma unroll
    for (int j = 0; j < 5; ++j) {
      const bool col_full = (cbk*4 + j) < 8;
      #pragma unroll
      for (int r = 0; r < 4; ++r) {
        bool ok = (row_full || (fq == 0 && r == 0)) && (col_full || (fr == 0));
        float p = __expf(acc[i][j][r] * SCALE - gmax);
        acc[i][j][r] = ok ? p : 0.0f;
      }
    }
  }

  // ---- ws: row sums (skip duplicated tile-col 4 for cbk=1, dup tile-row for rb=1) ----
  #pragma unroll
  for (int i = 0; i < 5; ++i) {
    if (!(rb == 1 && i == 0)) {
      #pragma unroll
      for (int r = 0; r < 4; ++r) {
        float rs = 0.f;
        #pragma unroll
        for (int j = 0; j < 5; ++j)
          if (!(cbk == 1 && j == 0)) rs += acc[i][j][r];
        rs += __shfl_xor(rs, 1); rs += __shfl_xor(rs, 2);
        rs += __shfl_xor(rs, 4); rs += __shfl_xor(rs, 8);
        if (fr == 0) ws_p[cbk][16*(rb*4 + i) + fq*4 + r] = rs;
      }
    }
  }
  // ---- wt: col sums ----
  #pragma unroll
  for (int j = 0; j < 5; ++j) {
    if (!(cbk == 1 && j == 0)) {
      float cs = 0.f;
      #pragma unroll
      for (int i = 0; i < 5; ++i)
        if (!(rb == 1 && i == 0)) {
          #pragma unroll
          for (int r = 0; r < 4; ++r) cs += acc[i][j][r];
        }
      cs += __shfl_xor(cs, 16); cs += __shfl_xor(cs, 32);
      if (lane < 16) wt_p[rb][16*(cbk*4 + j) + fr] = cs;
    }
  }
  __syncthreads();

  // ---- Z and invZ ----
  float zv = (tid < 144) ? (ws_p[0][tid] + ws_p[1][tid]) : 0.f;
  #pragma unroll
  for (int off = 32; off > 0; off >>= 1) zv += __shfl_xor(zv, off);
  if (lane == 0) red[4 + w] = zv;
  __syncthreads();
  const float invZ = 1.0f / (red[4] + red[5] + red[6] + red[7]);

  // ---- contexts: thread handles k = 2*tid, 2*tid+1 ----
  const int k2 = tid * 2;
  float sa0 = 0.f, sa1 = 0.f, ta0 = 0.f, ta1 = 0.f;
  for (int s = 0; s < SP; ++s) {
    float wsv = ws_p[0][s] + ws_p[1][s];
    float wtv = wt_p[0][s] + wt_p[1][s];
    unsigned us = *(const unsigned*)(skg + ((size_t)s << 9) + k2);
    unsigned ut = *(const unsigned*)(tkg + ((size_t)s << 9) + k2);
    sa0 = fmaf(wsv, __uint_as_float(us << 16), sa0);
    sa1 = fmaf(wsv, __uint_as_float(us & 0xFFFF0000u), sa1);
    ta0 = fmaf(wtv, __uint_as_float(ut << 16), ta0);
    ta1 = fmaf(wtv, __uint_as_float(ut & 0xFFFF0000u), ta1);
  }
  float2 so = make_float2(sa0 * invZ, sa1 * invZ);
  float2 to = make_float2(ta0 * invZ, ta1 * invZ);
  *(float2*)(s_ctx + (size_t)gid*HD + k2) = so;
  *(float2*)(t_ctx + (size_t)gid*HD + k2) = to;
}

// ---------------------------------------------------------------------------
// out = tanh([query | s_ctx | t_ctx] @ Wo + bo) ; K = 3*512
// ---------------------------------------------------------------------------
__global__ __launch_bounds__(256) void gemm3_tanh(
    const float* __restrict__ A0, const float* __restrict__ A1,
    const float* __restrict__ A2, const float* __restrict__ W,
    const float* __restrict__ bias, float* __restrict__ C, int M, int N)
{
  __shared__ float At[16*68];
  __shared__ float Bt[16*68];
  const int tid = threadIdx.x;
  const int tx = tid & 15, ty = tid >> 4;
  const int bm = blockIdx.x * 64, bn = blockIdx.y * 64;
  const int c  = tid & 15, r0 = tid >> 4;
  const int cb = tid & 63, rb0 = tid >> 6;
  float acc[4][4] = {};

  for (int k0 = 0; k0 < 1536; k0 += 16) {
    const float* Ap = (k0 < 512) ? A0 : (k0 < 1024) ? A1 : A2;
    const int kloc = k0 & 511;
    #pragma unroll
    for (int i = 0; i < 4; ++i) {
      int r = r0 + 16*i;
      At[c*68 + r] = Ap[(size_t)(bm + r)*512 + (kloc + c)];
    }
    #pragma unroll
    for (int i = 0; i < 4; ++i) {
      int r = rb0 + 4*i;
      Bt[r*68 + cb] = W[(size_t)(k0 + r)*N + (bn + cb)];
    }
    __syncthreads();
    #pragma unroll
    for (int kk = 0; kk < 16; ++kk) {
      const float4 a4 = *(const float4*)&At[kk*68 + ty*4];
      const float4 b4 = *(const float4*)&Bt[kk*68 + tx*4];
      const float av[4] = {a4.x, a4.y, a4.z, a4.w};
      const float bv[4] = {b4.x, b4.y, b4.z, b4.w};
      #pragma unroll
      for (int i = 0; i < 4; ++i)
        #pragma unroll
        for (int j = 0; j < 4; ++j)
          acc[i][j] = fmaf(av[i], bv[j], acc[i][j]);
    }
    __syncthreads();
  }
  #pragma unroll
  for (int i = 0; i < 4; ++i) {
    int m = bm + ty*4 + i;
    #pragma unroll
    for (int j = 0; j < 4; ++j) {
      int n = bn + tx*4 + j;
      C[(size_t)m*N + n] = tanhf(acc[i][j] + bias[n]);
    }
  }
}

extern "C" void kernel_launch(void* const* d_in, const int* in_sizes, int n_in,
                              void* d_out, int out_size, void* d_ws, size_t ws_size,
                              hipStream_t stream) {
  (void)in_sizes; (void)n_in; (void)out_size; (void)ws_size;
  const float* query = (const float*)d_in[0];
  const float* src   = (const float*)d_in[1];
  const float* trg   = (const float*)d_in[2];
  const float* Wq    = (const float*)d_in[3];
  const float* bq    = (const float*)d_in[4];
  const float* Wsm   = (const float*)d_in[5];
  const float* bs    = (const float*)d_in[6];
  const float* Wtm   = (const float*)d_in[7];
  const float* bt    = (const float*)d_in[8];
  const float* Wo    = (const float*)d_in[9];
  const float* bo    = (const float*)d_in[10];
  float* out = (float*)d_out;

  // workspace layout: q(f32) | skey(bf16,160rows) | tkey(bf16) | sctx | tctx
  char* wsb = (char*)d_ws;
  float* qbuf = (float*)wsb;                                   // 4096*512*4 = 8388608
  unsigned short* skb = (unsigned short*)(wsb + 8388608);      // 16*160*512*2 = 2621440
  unsigned short* tkb = (unsigned short*)(wsb + 8388608 + 2621440);
  float* sctx = (float*)(wsb + 8388608 + 2*2621440);           // 8388608
  float* tctx = (float*)(wsb + 8388608 + 2*2621440 + 8388608);

  dim3 blk(256);
  gemm_bias<<<dim3(MQ/64, HD/64), blk, 0, stream>>>(query, Wq, bq, qbuf, MQ, HD, HD);
  gemm_bias_bf16<<<dim3(2048/64, HD/64), blk, 0, stream>>>(src, Wsm, bs, skb, 2048, HD, HD);
  gemm_bias_bf16<<<dim3(2048/64, HD/64), blk, 0, stream>>>(trg, Wtm, bt, tkb, 2048, HD, HD);
  write_pad_bf16<<<dim3(16*32*512/256), blk, 0, stream>>>(skb, bs, tkb, bt);
  attn_kernel<<<dim3(MQ), blk, 0, stream>>>(qbuf, skb, tkb, sctx, tctx);
  gemm3_tanh<<<dim3(MQ/64, HD/64), blk, 0, stream>>>(query, sctx, tctx, Wo, bo, out, MQ, HD);
}

// Round 3
// 284.992 us; speedup vs baseline: 4.5264x; 2.5214x over previous
//
#include <hip/hip_runtime.h>
#include <math.h>

// Problem constants (fixed by the reference)
#define HD 512          // Q_DIM = F_DIM = H_DIM = OUT_DIM = 512
#define SP 129          // S+1 = T+1
#define RPAD 160        // padded key rows per batch (129 used, rest zero)
#define NBATCH 16
#define MQ 4096         // 16*256 query rows
#define SCALE 0.04419417382415922f  // 1/sqrt(512)

typedef _Float16 f16;
typedef _Float16 f16x8 __attribute__((ext_vector_type(8)));
typedef _Float16 f16x4 __attribute__((ext_vector_type(4)));
typedef _Float16 f16x2 __attribute__((ext_vector_type(2)));
typedef float f32x4  __attribute__((ext_vector_type(4)));

// ---------------------------------------------------------------------------
// flat f32 -> f16 convert (8 elems/thread)
// ---------------------------------------------------------------------------
__global__ __launch_bounds__(256) void conv_f32_f16(
    const float* __restrict__ a, f16* __restrict__ o, int n)
{
  int base = (blockIdx.x * 256 + threadIdx.x) * 8;
  if (base < n) {
    float4 x = *(const float4*)(a + base);
    float4 y = *(const float4*)(a + base + 4);
    f16x8 v = { (f16)x.x, (f16)x.y, (f16)x.z, (f16)x.w,
                (f16)y.x, (f16)y.y, (f16)y.z, (f16)y.w };
    *(f16x8*)(o + base) = v;
  }
}

// ---------------------------------------------------------------------------
// W[K][N] f32 -> WT[N][K] f16 (transpose + convert), 64x64 LDS tiles
// ---------------------------------------------------------------------------
__global__ __launch_bounds__(256) void convT_f32_f16(
    const float* __restrict__ W, f16* __restrict__ WT, int K, int N)
{
  __shared__ float t[64][65];
  const int k0 = blockIdx.x * 64, n0 = blockIdx.y * 64;
  const int tid = threadIdx.x;
  const int r = tid >> 4, c4 = (tid & 15) * 4;
  #pragma unroll
  for (int i = 0; i < 4; ++i) {
    int k = r + 16*i;
    float4 v = *(const float4*)(W + (size_t)(k0 + k)*N + n0 + c4);
    t[k][c4] = v.x; t[k][c4+1] = v.y; t[k][c4+2] = v.z; t[k][c4+3] = v.w;
  }
  __syncthreads();
  #pragma unroll
  for (int i = 0; i < 4; ++i) {
    int n = r + 16*i;
    f16x4 v = { (f16)t[c4][n], (f16)t[c4+1][n], (f16)t[c4+2][n], (f16)t[c4+3][n] };
    *(f16x4*)(WT + (size_t)(n0 + n)*K + k0 + c4) = v;
  }
}

// ---------------------------------------------------------------------------
// f16 MFMA GEMM: C[M,N] = concat_seg(A)[M, NSEG*512] @ WT^T + bias
// WT is [N][K] f16 (pre-transposed). 64x64 tile, 4 waves, 16x16x32 MFMA.
// MODE 0: f16 out; MODE 1: f16 out + key row remap (128/batch -> 160/batch);
// MODE 2: f32 out with tanh.
// ---------------------------------------------------------------------------
template<int NSEG, int MODE>
__global__ __launch_bounds__(256) void gemm_f16(
    const f16* __restrict__ A0, const f16* __restrict__ A1,
    const f16* __restrict__ A2, const f16* __restrict__ WT,
    const float* __restrict__ bias, void* __restrict__ Cv, int M, int N)
{
  __shared__ __align__(16) f16 As[64*64];
  __shared__ __align__(16) f16 Bs[64*64];
  const int KTOT = NSEG * 512;
  const int tid  = threadIdx.x;
  const int lane = tid & 63;
  const int w    = tid >> 6;
  const int wr   = w & 1, wc = w >> 1;
  const int fq   = lane >> 4, fr = lane & 15;
  const int bm = blockIdx.x * 64, bn = blockIdx.y * 64;

  f32x4 acc[2][2] = {};

  for (int k0 = 0; k0 < KTOT; k0 += 64) {
    const int seg  = k0 >> 9;
    const f16* Ap  = (NSEG == 1) ? A0 : (seg == 0 ? A0 : (seg == 1 ? A1 : A2));
    const int kloc = k0 & 511;
    #pragma unroll
    for (int i = 0; i < 2; ++i) {
      int idx = tid + 256*i;
      int r = idx >> 3, c = idx & 7;
      const uint4 va = *(const uint4*)(Ap + (size_t)(bm + r)*512 + kloc + c*8);
      const uint4 vb = *(const uint4*)(WT + (size_t)(bn + r)*KTOT + k0 + c*8);
      int o = ((r << 7) + (c << 4)) ^ ((r & 7) << 4);
      *(uint4*)((char*)As + o) = va;
      *(uint4*)((char*)Bs + o) = vb;
    }
    __syncthreads();
    #pragma unroll
    for (int ks = 0; ks < 2; ++ks) {
      f16x8 af[2], bf_[2];
      #pragma unroll
      for (int i = 0; i < 2; ++i) {
        int ra = wr*32 + i*16 + fr;
        int oa = ((ra << 7) + (ks << 6) + (fq << 4)) ^ ((ra & 7) << 4);
        af[i] = *(const f16x8*)((const char*)As + oa);
        int rb = wc*32 + i*16 + fr;
        int ob = ((rb << 7) + (ks << 6) + (fq << 4)) ^ ((rb & 7) << 4);
        bf_[i] = *(const f16x8*)((const char*)Bs + ob);
      }
      #pragma unroll
      for (int i = 0; i < 2; ++i)
        #pragma unroll
        for (int j = 0; j < 2; ++j)
          acc[i][j] = __builtin_amdgcn_mfma_f32_16x16x32_f16(af[i], bf_[j], acc[i][j], 0, 0, 0);
    }
    __syncthreads();
  }

  #pragma unroll
  for (int i = 0; i < 2; ++i) {
    #pragma unroll
    for (int j = 0; j < 2; ++j) {
      int n = bn + wc*32 + j*16 + fr;
      float bv = bias[n];
      #pragma unroll
      for (int r = 0; r < 4; ++r) {
        int m = bm + wr*32 + i*16 + fq*4 + r;
        float x = acc[i][j][r] + bv;
        if (MODE == 0) {
          ((f16*)Cv)[(size_t)m*N + n] = (f16)x;
        } else if (MODE == 1) {
          int mo = (m >> 7) * RPAD + (m & 127);
          ((f16*)Cv)[(size_t)mo*N + n] = (f16)x;
        } else {
          x = fminf(fmaxf(x, -20.f), 20.f);
          float e = __expf(2.0f * x);
          ((float*)Cv)[(size_t)m*N + n] = (e - 1.0f) / (e + 1.0f);
        }
      }
    }
  }
}

// Rows 128..159 of each batch: row 128 = bias (reference pad row), rest 0.
__global__ void write_pad_f16(f16* __restrict__ skey, const float* __restrict__ bs,
                              f16* __restrict__ tkey, const float* __restrict__ bt)
{
  int i = blockIdx.x * 256 + threadIdx.x;   // 16 batches * 32 rows * 512
  int b = i >> 14;
  int r = 128 + ((i >> 9) & 31);
  int k = i & 511;
  size_t off = ((size_t)b*RPAD + r)*HD + k;
  skey[off] = (r == 128) ? (f16)bs[k] : (f16)0.f;
  tkey[off] = (r == 128) ? (f16)bt[k] : (f16)0.f;
}

// ---------------------------------------------------------------------------
// Fused trilinear attention, f16 MFMA. One block (4 waves) per query row.
// S = (q .* s_key) @ t_key^T over K=512, M=N padded to 144; row 128 of keys is
// the reference pad row. P never materialized: only gmax, row sums ws and col
// sums wt; s_ctx = ws@s_key, t_ctx = wt@t_key.
// ---------------------------------------------------------------------------
__global__ __launch_bounds__(256, 3) void attn_kernel(
    const f16* __restrict__ qg,      // (4096, 512)
    const f16* __restrict__ s_key,   // (16, 160, 512)
    const f16* __restrict__ t_key,   // (16, 160, 512)
    f16* __restrict__ s_ctx,         // (4096, 512)
    f16* __restrict__ t_ctx)         // (4096, 512)
{
  __shared__ __align__(16) f16 skt[144*64];  // XOR-swizzled K-tile
  __shared__ __align__(16) f16 tkt[144*64];
  __shared__ __align__(16) f16 qs[HD];
  __shared__ float ws_p[2][144];
  __shared__ float wt_p[2][144];
  __shared__ float red[8];

  const int tid  = threadIdx.x;
  const int lane = tid & 63;
  const int w    = tid >> 6;
  const int rb   = w & 1;    // tile-row block {0..4} / {4..8} (overlap at 4)
  const int cbk  = w >> 1;   // tile-col block
  const int fq   = lane >> 4;
  const int fr   = lane & 15;

  // XCD-chunked swizzle: 4096 blocks -> 512 consecutive rows per XCD
  const int gid = ((int)blockIdx.x & 7) * 512 + ((int)blockIdx.x >> 3);
  const int b   = gid >> 8;
  const f16* qr  = qg + (size_t)gid * HD;
  const f16* skg = s_key + (size_t)b * RPAD * HD;
  const f16* tkg = t_key + (size_t)b * RPAD * HD;

  if (tid < 64) *(uint4*)(qs + tid*8) = *(const uint4*)(qr + tid*8);

  f32x4 acc[5][5] = {};

  for (int kt = 0; kt < 8; ++kt) {
    const int k0 = kt * 64;
    #pragma unroll
    for (int i = 0; i < 5; ++i) {
      int idx = tid + 256*i;
      if (idx < 1152) {
        int r = idx >> 3, c = idx & 7;
        size_t goff = ((size_t)r << 9) + k0 + (c << 3);
        const uint4 vs = *(const uint4*)(skg + goff);
        const uint4 vt = *(const uint4*)(tkg + goff);
        int o = ((r << 7) + (c << 4)) ^ ((r & 7) << 4);
        *(uint4*)((char*)skt + o) = vs;
        *(uint4*)((char*)tkt + o) = vt;
      }
    }
    __syncthreads();
    #pragma unroll
    for (int ks = 0; ks < 2; ++ks) {
      const f16x8 qv = *(const f16x8*)(qs + k0 + ks*32 + fq*8);
      f16x8 af[5], bf_[5];
      #pragma unroll
      for (int i = 0; i < 5; ++i) {
        int ra = 16*(rb*4 + i) + fr;
        int oa = ((ra << 7) + (ks << 6) + (fq << 4)) ^ ((ra & 7) << 4);
        af[i] = *(const f16x8*)((const char*)skt + oa) * qv;  // v_pk_mul_f16
        int rbx = 16*(cbk*4 + i) + fr;
        int ob = ((rbx << 7) + (ks << 6) + (fq << 4)) ^ ((rbx & 7) << 4);
        bf_[i] = *(const f16x8*)((const char*)tkt + ob);
      }
      #pragma unroll
      for (int i = 0; i < 5; ++i)
        #pragma unroll
        for (int j = 0; j < 5; ++j)
          acc[i][j] = __builtin_amdgcn_mfma_f32_16x16x32_f16(af[i], bf_[j], acc[i][j], 0, 0, 0);
    }
    __syncthreads();
  }

  // ---- masked max over valid (s<129, t<129) ----
  float m = -3e38f;
  #pragma unroll
  for (int i = 0; i < 5; ++i) {
    const bool row_full = (rb*4 + i) < 8;
    #pragma unroll
    for (int j = 0; j < 5; ++j) {
      const bool col_full = (cbk*4 + j) < 8;
      #pragma unroll
      for (int r = 0; r < 4; ++r) {
        bool ok = (row_full || (fq == 0 && r == 0)) && (col_full || (fr == 0));
        m = ok ? fmaxf(m, acc[i][j][r]) : m;
      }
    }
  }
  #pragma unroll
  for (int off = 32; off > 0; off >>= 1) m = fmaxf(m, __shfl_xor(m, off));
  if (lane == 0) red[w] = m;
  __syncthreads();
  const float gmax = fmaxf(fmaxf(red[0], red[1]), fmaxf(red[2], red[3])) * SCALE;

  // ---- exp in registers (invalid -> 0) ----
  #pragma unroll
  for (int i = 0; i < 5; ++i) {
    const bool row_full = (rb*4 + i) < 8;
    #pragma unroll
    for (int j = 0; j < 5; ++j) {
      const bool col_full = (cbk*4 + j) < 8;
      #pragma unroll
      for (int r = 0; r < 4; ++r) {
        bool ok = (row_full || (fq == 0 && r == 0)) && (col_full || (fr == 0));
        float p = __expf(acc[i][j][r] * SCALE - gmax);
        acc[i][j][r] = ok ? p : 0.0f;
      }
    }
  }

  // ---- ws: row sums (dedup overlapped tile-row/col 4) ----
  #pragma unroll
  for (int i = 0; i < 5; ++i) {
    if (!(rb == 1 && i == 0)) {
      #pragma unroll
      for (int r = 0; r < 4; ++r) {
        float rs = 0.f;
        #pragma unroll
        for (int j = 0; j < 5; ++j)
          if (!(cbk == 1 && j == 0)) rs += acc[i][j][r];
        rs += __shfl_xor(rs, 1); rs += __shfl_xor(rs, 2);
        rs += __shfl_xor(rs, 4); rs += __shfl_xor(rs, 8);
        if (fr == 0) ws_p[cbk][16*(rb*4 + i) + fq*4 + r] = rs;
      }
    }
  }
  // ---- wt: col sums ----
  #pragma unroll
  for (int j = 0; j < 5; ++j) {
    if (!(cbk == 1 && j == 0)) {
      float cs = 0.f;
      #pragma unroll
      for (int i = 0; i < 5; ++i)
        if (!(rb == 1 && i == 0)) {
          #pragma unroll
          for (int r = 0; r < 4; ++r) cs += acc[i][j][r];
        }
      cs += __shfl_xor(cs, 16); cs += __shfl_xor(cs, 32);
      if (lane < 16) wt_p[rb][16*(cbk*4 + j) + fr] = cs;
    }
  }
  __syncthreads();

  // ---- Z and invZ ----
  float zv = (tid < 144) ? (ws_p[0][tid] + ws_p[1][tid]) : 0.f;
  #pragma unroll
  for (int off = 32; off > 0; off >>= 1) zv += __shfl_xor(zv, off);
  if (lane == 0) red[4 + w] = zv;
  __syncthreads();
  const float invZ = 1.0f / (red[4] + red[5] + red[6] + red[7]);

  // ---- contexts: thread handles k = 2*tid, 2*tid+1 ----
  const int k2 = tid * 2;
  float sa0 = 0.f, sa1 = 0.f, ta0 = 0.f, ta1 = 0.f;
  for (int s = 0; s < SP; ++s) {
    float wsv = ws_p[0][s] + ws_p[1][s];
    float wtv = wt_p[0][s] + wt_p[1][s];
    f16x2 ps = *(const f16x2*)(skg + ((size_t)s << 9) + k2);
    f16x2 pt = *(const f16x2*)(tkg + ((size_t)s << 9) + k2);
    sa0 = fmaf(wsv, (float)ps[0], sa0);
    sa1 = fmaf(wsv, (float)ps[1], sa1);
    ta0 = fmaf(wtv, (float)pt[0], ta0);
    ta1 = fmaf(wtv, (float)pt[1], ta1);
  }
  f16x2 so = { (f16)(sa0 * invZ), (f16)(sa1 * invZ) };
  f16x2 to = { (f16)(ta0 * invZ), (f16)(ta1 * invZ) };
  *(f16x2*)(s_ctx + (size_t)gid*HD + k2) = so;
  *(f16x2*)(t_ctx + (size_t)gid*HD + k2) = to;
}

extern "C" void kernel_launch(void* const* d_in, const int* in_sizes, int n_in,
                              void* d_out, int out_size, void* d_ws, size_t ws_size,
                              hipStream_t stream) {
  (void)in_sizes; (void)n_in; (void)out_size; (void)ws_size;
  const float* query = (const float*)d_in[0];
  const float* src   = (const float*)d_in[1];
  const float* trg   = (const float*)d_in[2];
  const float* Wq    = (const float*)d_in[3];
  const float* bq    = (const float*)d_in[4];
  const float* Wsm   = (const float*)d_in[5];
  const float* bs    = (const float*)d_in[6];
  const float* Wtm   = (const float*)d_in[7];
  const float* bt    = (const float*)d_in[8];
  const float* Wo    = (const float*)d_in[9];
  const float* bo    = (const float*)d_in[10];
  float* out = (float*)d_out;

  // workspace layout (f16 buffers), ~32.3 MB total
  char* p = (char*)d_ws;
  f16* query_h = (f16*)p;                 p += (size_t)MQ*HD*2;        // 4 MB
  f16* src_h   = (f16*)p;                 p += (size_t)2048*HD*2;      // 2 MB
  f16* trg_h   = (f16*)p;                 p += (size_t)2048*HD*2;      // 2 MB
  f16* WqT     = (f16*)p;                 p += (size_t)HD*HD*2;        // 0.5 MB
  f16* WsT     = (f16*)p;                 p += (size_t)HD*HD*2;
  f16* WtT     = (f16*)p;                 p += (size_t)HD*HD*2;
  f16* WoT     = (f16*)p;                 p += (size_t)1536*HD*2;      // 1.5 MB
  f16* q_h     = (f16*)p;                 p += (size_t)MQ*HD*2;        // 4 MB
  f16* skey    = (f16*)p;                 p += (size_t)NBATCH*RPAD*HD*2; // 2.56 MB
  f16* tkey    = (f16*)p;                 p += (size_t)NBATCH*RPAD*HD*2;
  f16* sctx    = (f16*)p;                 p += (size_t)MQ*HD*2;        // 4 MB
  f16* tctx    = (f16*)p;                 p += (size_t)MQ*HD*2;

  dim3 blk(256);
  conv_f32_f16<<<dim3(MQ*HD/8/256), blk, 0, stream>>>(query, query_h, MQ*HD);
  conv_f32_f16<<<dim3(2048*HD/8/256), blk, 0, stream>>>(src, src_h, 2048*HD);
  conv_f32_f16<<<dim3(2048*HD/8/256), blk, 0, stream>>>(trg, trg_h, 2048*HD);
  convT_f32_f16<<<dim3(8, 8), blk, 0, stream>>>(Wq, WqT, HD, HD);
  convT_f32_f16<<<dim3(8, 8), blk, 0, stream>>>(Wsm, WsT, HD, HD);
  convT_f32_f16<<<dim3(8, 8), blk, 0, stream>>>(Wtm, WtT, HD, HD);
  convT_f32_f16<<<dim3(24, 8), blk, 0, stream>>>(Wo, WoT, 1536, HD);

  gemm_f16<1,0><<<dim3(64, 8), blk, 0, stream>>>(query_h, nullptr, nullptr, WqT, bq, q_h, MQ, HD);
  gemm_f16<1,1><<<dim3(32, 8), blk, 0, stream>>>(src_h, nullptr, nullptr, WsT, bs, skey, 2048, HD);
  gemm_f16<1,1><<<dim3(32, 8), blk, 0, stream>>>(trg_h, nullptr, nullptr, WtT, bt, tkey, 2048, HD);
  write_pad_f16<<<dim3(16*32*512/256), blk, 0, stream>>>(skey, bs, tkey, bt);

  attn_kernel<<<dim3(MQ), blk, 0, stream>>>(q_h, skey, tkey, sctx, tctx);

  gemm_f16<3,2><<<dim3(64, 8), blk, 0, stream>>>(query_h, sctx, tctx, WoT, bo, out, MQ, HD);
}